// Round 1
// baseline (14800.372 us; speedup 1.0000x reference)
//
#include <hip/hip_runtime.h>

// Persistent-grid DNC encoder for MI355X (gfx950).
// 128 blocks x 256 threads, ~124KB dynamic LDS/block -> 1 block/CU -> all
// blocks co-resident (no cooperative launch needed). Custom grid barrier via
// per-slot arrival counters in d_ws (zeroed with hipMemsetAsync each launch).

constexpr int NBLK = 128;     // grid blocks
constexpr int BS   = 256;     // threads per block
constexpr int BQ   = 32;      // batch
constexpr int TT   = 256;     // time steps
constexpr int HH   = 512;     // hidden
constexpr int RH   = 4;       // read heads
constexpr int NC   = 64;      // cells
constexpr int XI   = 471;
constexpr int XIP  = 480;     // padded xi row stride (floats)
constexpr int KG   = 1280;    // gates K = 512(x)+256(r)+512(h)
constexpr int KGP  = 1288;    // padded LDS K stride (bf16) ; 644 words % 32 == 4
constexpr int WXP  = 520;     // padded W_xi K stride
constexpr int WOP  = 776;     // padded W_out K stride
constexpr float CLIPV = 50000.0f;
constexpr float EPSV  = 1e-6f;

typedef __bf16 bf16x8 __attribute__((ext_vector_type(8)));
typedef float  f32x4  __attribute__((ext_vector_type(4)));

// ---- LDS layout (bytes) ----
constexpr int OFF_WG   = 0;                      // 16*KGP bf16      = 41216
constexpr int OFF_WXI  = OFF_WG  + 16*KGP*2;     // 16*WXP bf16      = 16640
constexpr int OFF_WO   = OFF_WXI + 16*WXP*2;     // 16*WOP bf16      = 24832
constexpr int OFF_GT   = OFF_WO  + 16*WOP*2;     // 32*17 f32        = 2176
constexpr int OFF_CST  = OFF_GT  + 32*17*4;      // 32*4 f32         = 512
constexpr int OFF_DNC  = OFF_CST + 32*4*4;
constexpr int D_M    = 0;                        // 64*65 f32
constexpr int D_L    = D_M   + 64*65*4;
constexpr int D_XIR  = D_L   + 64*65*4;          // 480 f32
constexpr int D_WR   = D_XIR + XIP*4;            // 4*64
constexpr int D_FWD  = D_WR  + 256*4;
constexpr int D_BWD  = D_FWD + 256*4;
constexpr int D_SIMR = D_BWD + 256*4;
constexpr int D_VEC  = D_SIMR+ 256*4;            // 8 arrays of 64 f32
constexpr int D_SCAL = D_VEC + 8*64*4;           // 32 f32
constexpr int SMEM_BYTES = OFF_DNC + D_SCAL + 32*4;  // = 126848

__device__ __forceinline__ unsigned short f2b(float f) {
  unsigned u = __builtin_bit_cast(unsigned, f);
  u += 0x7fffu + ((u >> 16) & 1u);
  return (unsigned short)(u >> 16);
}
__device__ __forceinline__ float sigf(float x) { return 1.0f / (1.0f + expf(-x)); }
__device__ __forceinline__ float softplusf(float x) { return (x > 20.0f) ? x : log1pf(expf(x)); }
__device__ __forceinline__ float wsum(float v) {
  #pragma unroll
  for (int o = 32; o; o >>= 1) v += __shfl_xor(v, o, 64);
  return v;
}
__device__ __forceinline__ float wmaxr(float v) {
  #pragma unroll
  for (int o = 32; o; o >>= 1) v = fmaxf(v, __shfl_xor(v, o, 64));
  return v;
}
__device__ __forceinline__ f32x4 mfma16(bf16x8 a, bf16x8 b, f32x4 c) {
  return __builtin_amdgcn_mfma_f32_16x16x32_bf16(a, b, c, 0, 0, 0);
}

__device__ __forceinline__ void gbar(unsigned* bars, int slot) {
  __threadfence();            // publish this thread's global stores (agent scope)
  __syncthreads();
  if (threadIdx.x == 0) {
    unsigned prev = __hip_atomic_fetch_add(&bars[slot], 1u, __ATOMIC_ACQ_REL, __HIP_MEMORY_SCOPE_AGENT);
    if (prev + 1u < (unsigned)NBLK) {
      while (__hip_atomic_load(&bars[slot], __ATOMIC_RELAXED, __HIP_MEMORY_SCOPE_AGENT) < (unsigned)NBLK)
        __builtin_amdgcn_s_sleep(2);
    }
    (void)__hip_atomic_load(&bars[slot], __ATOMIC_ACQUIRE, __HIP_MEMORY_SCOPE_AGENT);
  }
  __syncthreads();
}

__global__ __launch_bounds__(BS, 1) void dnc_kernel(
    const int* __restrict__ src, const float* __restrict__ emb,
    const float* __restrict__ Wih, const float* __restrict__ Whh,
    const float* __restrict__ b_lstm, const float* __restrict__ W_xi,
    const float* __restrict__ b_xi, const float* __restrict__ W_out,
    const float* __restrict__ b_out, float* __restrict__ out,
    unsigned* __restrict__ bars, unsigned short* __restrict__ hbuf,
    unsigned short* __restrict__ rbuf, float* __restrict__ xibuf)
{
  extern __shared__ char smem[];
  __bf16* lWg  = (__bf16*)(smem + OFF_WG);
  __bf16* lWxi = (__bf16*)(smem + OFF_WXI);
  __bf16* lWo  = (__bf16*)(smem + OFF_WO);
  float*  gt   = (float*)(smem + OFF_GT);
  float*  cst  = (float*)(smem + OFF_CST);
  char*   dnc  = smem + OFF_DNC;
  float* Ml   = (float*)(dnc + D_M);
  float* Ll   = (float*)(dnc + D_L);
  float* xir  = (float*)(dnc + D_XIR);
  float* wrl  = (float*)(dnc + D_WR);
  float* fwd  = (float*)(dnc + D_FWD);
  float* bwd  = (float*)(dnc + D_BWD);
  float* simr = (float*)(dnc + D_SIMR);
  float* uu   = (float*)(dnc + D_VEC);
  float* pp   = uu + 64;
  float* wwl  = uu + 128;
  float* aas  = uu + 192;
  float* nrmo = uu + 256;
  float* nrmn = uu + 320;
  float* simw = uu + 384;
  float* er   = uu + 448;
  float* scal = (float*)(dnc + D_SCAL);
  // scal: [0]beta_w [1]g_a [2]g_w [3]wknrm [4..7]beta_r [8..11]rkn [12..15]free [16..27]pi

  const int tid  = threadIdx.x;
  const int blk  = blockIdx.x;
  const int lane = tid & 63;
  const int wv   = tid >> 6;
  const int q    = lane >> 4;
  const int n16  = lane & 15;
  const int j0   = blk << 2;    // h slice: columns j0..j0+3

  // ---------------- prepass: weights -> LDS (transposed, bf16) ----------------
  for (int e = tid; e < 16 * KG; e += BS) {
    int k = e >> 4, cc = e & 15;
    int gcol = ((cc >> 2) << 9) + j0 + (cc & 3);   // gate*512 + h-col
    float w = (k < 768) ? Wih[k * 2048 + gcol] : Whh[(k - 768) * 2048 + gcol];
    lWg[cc * KGP + k] = (__bf16)w;
  }
  if (blk < 30) {
    for (int e = tid; e < 16 * HH; e += BS) {
      int k = e >> 4, cc = e & 15;
      int col = (blk << 4) + cc;
      lWxi[cc * WXP + k] = (col < XI) ? (__bf16)W_xi[k * XI + col] : (__bf16)0.0f;
    }
  }
  if (blk >= 64 && blk < 96) {
    for (int e = tid; e < 16 * 768; e += BS) {
      int k = e >> 4, cc = e & 15;
      int col = ((blk - 64) << 4) + cc;
      lWo[cc * WOP + k] = (__bf16)W_out[k * HH + col];
    }
  }
  if (tid < 128) cst[tid] = 0.0f;
  if (blk < BQ) {
    for (int e = tid; e < 64 * 65; e += BS) { Ml[e] = 0.0f; Ll[e] = 0.0f; }
    if (tid < 64) { uu[tid] = 0.0f; pp[tid] = 0.0f; wwl[tid] = 0.0f; }
    wrl[tid] = 0.0f;   // 256 entries = 4*64
  }
  gbar(bars, 0);

  // y-phase lambda: computes y_{t-1}; valid for t in [1..TT]; runs on waves 2,3
  auto do_y = [&](int t) {
    const __bf16* hp = (const __bf16*)(hbuf + ((t + 1) & 1) * (BQ * HH));
    const __bf16* rp = (const __bf16*)rbuf;
    const int mt = wv - 2;
    const int bb = (mt << 4) + n16;
    f32x4 a0 = {0.f, 0.f, 0.f, 0.f}, a1 = {0.f, 0.f, 0.f, 0.f};
    #pragma unroll
    for (int ks = 0; ks < 24; ++ks) {
      const int kq = (ks << 5) + (q << 3);
      bf16x8 A = (ks < 16) ? *(const bf16x8*)(hp + bb * HH + kq)
                           : *(const bf16x8*)(rp + bb * (RH * NC) + (kq - 512));
      bf16x8 Bf = *(const bf16x8*)(lWo + n16 * WOP + kq);
      if (ks & 1) a1 = mfma16(A, Bf, a1); else a0 = mfma16(A, Bf, a0);
    }
    const int col = ((blk - 64) << 4) + n16;
    const float bias = b_out[col];
    #pragma unroll
    for (int j = 0; j < 4; ++j) {
      int row = (mt << 4) + (q << 2) + j;
      float y = a0[j] + a1[j] + bias;
      y = fminf(fmaxf(y, -CLIPV), CLIPV);
      out[(size_t)row * (TT * HH) + (size_t)(t - 1) * HH + col] = y;
    }
  };

  int slot = 1;
  for (int t = 0; t < TT; ++t) {
    const __bf16* hprev = (const __bf16*)(hbuf + ((t + 1) & 1) * (BQ * HH));
    unsigned short* hcur = hbuf + (t & 1) * (BQ * HH);

    // ---------------- phase A: gates (waves 0,1) + y_{t-1} (waves 2,3 on blocks 64..95)
    if (wv < 2) {
      const int bb = (wv << 4) + n16;
      const int srow = src[bb * TT + t];
      const float* ep = emb + (size_t)srow * HH + (q << 3);
      const __bf16* rp = (const __bf16*)rbuf;
      f32x4 a0 = {0.f, 0.f, 0.f, 0.f}, a1 = {0.f, 0.f, 0.f, 0.f};
      #pragma unroll
      for (int ks = 0; ks < 40; ++ks) {
        const int kq = (ks << 5) + (q << 3);
        bf16x8 A;
        if (ks < 16) {
          const float* p = ep + (ks << 5);
          #pragma unroll
          for (int j = 0; j < 8; ++j) A[j] = (__bf16)p[j];
        } else if (ks < 24) {
          A = *(const bf16x8*)(rp + bb * (RH * NC) + (kq - 512));
        } else {
          A = *(const bf16x8*)(hprev + bb * HH + (kq - 768));
        }
        bf16x8 Bf = *(const bf16x8*)(lWg + n16 * KGP + kq);
        if (ks & 1) a1 = mfma16(A, Bf, a1); else a0 = mfma16(A, Bf, a0);
      }
      const int gcol = ((n16 >> 2) << 9) + j0 + (n16 & 3);
      const float bias = b_lstm[gcol];
      #pragma unroll
      for (int j = 0; j < 4; ++j)
        gt[((wv << 4) + (q << 2) + j) * 17 + n16] = a0[j] + a1[j] + bias;
    } else if (blk >= 64 && blk < 96 && t > 0) {
      do_y(t);
    }
    __syncthreads();
    if (tid < 128) {           // LSTM state update for our 4 h-columns
      const int b = tid >> 2, i = tid & 3;
      float gi = gt[b * 17 + i],     gf = gt[b * 17 + 4 + i];
      float gg = gt[b * 17 + 8 + i], go = gt[b * 17 + 12 + i];
      float c = cst[tid];
      c = sigf(gf) * c + sigf(gi) * tanhf(gg);
      float h = sigf(go) * tanhf(c);
      cst[tid] = c;
      hcur[b * HH + j0 + i] = f2b(h);
    }
    gbar(bars, slot++);

    // ---------------- phase B: xi = h_t @ W_xi + b_xi (blocks 0..29)
    if (blk < 30 && wv < 2) {
      const __bf16* hc = (const __bf16*)hcur;
      const int bb = (wv << 4) + n16;
      f32x4 a0 = {0.f, 0.f, 0.f, 0.f}, a1 = {0.f, 0.f, 0.f, 0.f};
      #pragma unroll
      for (int ks = 0; ks < 16; ++ks) {
        const int kq = (ks << 5) + (q << 3);
        bf16x8 A = *(const bf16x8*)(hc + bb * HH + kq);
        bf16x8 Bf = *(const bf16x8*)(lWxi + n16 * WXP + kq);
        if (ks & 1) a1 = mfma16(A, Bf, a1); else a0 = mfma16(A, Bf, a0);
      }
      const int col = (blk << 4) + n16;
      if (col < XI) {
        const float bias = b_xi[col];
        #pragma unroll
        for (int j = 0; j < 4; ++j) {
          int row = (wv << 4) + (q << 2) + j;
          xibuf[row * XIP + col] = a0[j] + a1[j] + bias;
        }
      }
    }
    gbar(bars, slot++);

    // ---------------- phase C: DNC memory update, one block per batch element
    if (blk < BQ) {
      for (int e = tid; e < XIP; e += BS) xir[e] = (e < XI) ? xibuf[blk * XIP + e] : 0.0f;
      __syncthreads();
      if (tid == 0) {
        scal[0] = 1.0f + softplusf(xir[324]);   // beta_w
        scal[1] = sigf(xir[457]);               // g_a
        scal[2] = sigf(xir[458]);               // g_w
      }
      if (tid >= 4 && tid < 8) {
        int r = tid - 4;
        scal[4 + r]  = 1.0f + softplusf(xir[256 + r]);  // beta_r
        scal[12 + r] = sigf(xir[453 + r]);              // free
        float p0 = xir[459 + r * 3], p1 = xir[460 + r * 3], p2 = xir[461 + r * 3];
        float m = fmaxf(p0, fmaxf(p1, p2));
        float e0 = expf(p0 - m), e1 = expf(p1 - m), e2 = expf(p2 - m);
        float s = e0 + e1 + e2;
        scal[16 + r * 3 + 0] = e0 / s;
        scal[16 + r * 3 + 1] = e1 / s;
        scal[16 + r * 3 + 2] = e2 / s;
      }
      if (tid >= 64 && tid < 128) er[tid - 64] = sigf(xir[325 + (tid - 64)]);
      __syncthreads();
      // -- step 2: old norms / write-key sim / usage + stable sort + allocation
      if (wv == 0) {
        float s = 0.f;
        for (int w = 0; w < 64; ++w) { float m = Ml[lane * 65 + w]; s += m * m; }
        nrmo[lane] = sqrtf(s) + EPSV;
      } else if (wv == 1) {
        float d = 0.f;
        for (int w = 0; w < 64; ++w) d += Ml[lane * 65 + w] * xir[260 + w];
        simw[lane] = d;
        float v = xir[260 + lane];
        float s2 = wsum(v * v);
        if (lane == 0) scal[3] = sqrtf(s2) + EPSV;
      } else if (wv == 2) {
        float psi = 1.f;
        #pragma unroll
        for (int r = 0; r < 4; ++r) psi *= (1.f - scal[12 + r] * wrl[r * 64 + lane]);
        float un = uu[lane], w_ = wwl[lane];
        un = (un + w_ - un * w_) * psi;
        uu[lane] = un;
        // stable bitonic argsort ascending by (u, index)
        float v = un; int id = lane;
        for (int k = 2; k <= 64; k <<= 1) {
          for (int j2 = k >> 1; j2 > 0; j2 >>= 1) {
            float ov = __shfl_xor(v, j2, 64);
            int   oi = __shfl_xor(id, j2, 64);
            bool up    = ((lane & k) == 0);
            bool lower = ((lane & j2) == 0);
            bool lt = (v < ov) || (v == ov && id < oi);
            bool keep = (lower == up) ? lt : !lt;
            if (!keep) { v = ov; id = oi; }
          }
        }
        float cp = v;   // inclusive cumprod of sorted u
        for (int d2 = 1; d2 < 64; d2 <<= 1) {
          float o = __shfl_up(cp, d2, 64);
          if (lane >= d2) cp *= o;
        }
        float pe = __shfl_up(cp, 1, 64);
        if (lane == 0) pe = 1.0f;
        aas[id] = (1.0f - v) * pe;
      }
      __syncthreads();
      // -- step 3: write content weights -> ww
      if (wv == 0) {
        float x = simw[lane] / (nrmo[lane] * scal[3]) * scal[0];
        float mx = wmaxr(x);
        float e = expf(x - mx);
        float s = wsum(e);
        float cw = e / s;
        wwl[lane] = scal[2] * (scal[1] * aas[lane] + (1.f - scal[1]) * cw);
      }
      __syncthreads();
      // -- step 4: M and L updates (old p)
      {
        const int n = tid >> 2, c4 = (tid & 3) << 4;
        float wwn = wwl[n];
        #pragma unroll
        for (int w = 0; w < 16; ++w) {
          int wj = c4 + w;
          Ml[n * 65 + wj] = Ml[n * 65 + wj] * (1.f - wwn * er[wj]) + wwn * xir[389 + wj];
        }
        #pragma unroll
        for (int w = 0; w < 16; ++w) {
          int m2 = c4 + w;
          float Lv = (n == m2) ? 0.f
                   : ((1.f - wwn - wwl[m2]) * Ll[n * 65 + m2] + wwn * pp[m2]);
          Ll[n * 65 + m2] = Lv;
        }
      }
      __syncthreads();
      // -- step 5: fwd/bwd (old wr, new L), read-key sims (new M), new norms
      {
        float f = 0.f, bw2 = 0.f, d = 0.f;
        for (int m2 = 0; m2 < 64; ++m2) {
          float wrm = wrl[wv * 64 + m2];
          f   += Ll[lane * 65 + m2] * wrm;
          bw2 += Ll[m2 * 65 + lane] * wrm;
        }
        fwd[wv * 64 + lane] = f;
        bwd[wv * 64 + lane] = bw2;
        for (int w = 0; w < 64; ++w) d += Ml[lane * 65 + w] * xir[wv * 64 + w];
        simr[wv * 64 + lane] = d;
        float v = xir[wv * 64 + lane];
        float s2 = wsum(v * v);
        if (lane == 0) scal[8 + wv] = sqrtf(s2) + EPSV;
        if (wv == 0) {
          float s = 0.f;
          for (int w = 0; w < 64; ++w) { float m = Ml[lane * 65 + w]; s += m * m; }
          nrmn[lane] = sqrtf(s) + EPSV;
        }
      }
      __syncthreads();
      // -- step 6: read content weights, new wr, p update
      {
        float x = simr[wv * 64 + lane] / (nrmn[lane] * scal[8 + wv]) * scal[4 + wv];
        float mx = wmaxr(x);
        float e = expf(x - mx);
        float s = wsum(e);
        float cw = e / s;
        float wrn = scal[16 + wv * 3 + 0] * bwd[wv * 64 + lane]
                  + scal[16 + wv * 3 + 1] * cw
                  + scal[16 + wv * 3 + 2] * fwd[wv * 64 + lane];
        wrl[wv * 64 + lane] = wrn;
        if (wv == 3) {
          float s3 = wsum(wwl[lane]);
          pp[lane] = (1.f - s3) * pp[lane] + wwl[lane];
        }
      }
      __syncthreads();
      // -- step 7: r = wr @ M -> rbuf (bf16)
      {
        float rv = 0.f;
        for (int n2 = 0; n2 < 64; ++n2) rv += wrl[wv * 64 + n2] * Ml[n2 * 65 + lane];
        rbuf[blk * (RH * NC) + wv * 64 + lane] = f2b(rv);
      }
    }
    gbar(bars, slot++);
  }

  // final y_{T-1}
  if (blk >= 64 && blk < 96 && wv >= 2) do_y(TT);
}

extern "C" void kernel_launch(void* const* d_in, const int* in_sizes, int n_in,
                              void* d_out, int out_size, void* d_ws, size_t ws_size,
                              hipStream_t stream) {
  const int*   src    = (const int*)d_in[0];
  // d_in[1] = source_lengths (unused)
  const float* emb    = (const float*)d_in[2];
  const float* Wih    = (const float*)d_in[3];
  const float* Whh    = (const float*)d_in[4];
  const float* b_lstm = (const float*)d_in[5];
  const float* W_xi   = (const float*)d_in[6];
  const float* b_xi   = (const float*)d_in[7];
  const float* W_out  = (const float*)d_in[8];
  const float* b_out  = (const float*)d_in[9];
  float* out = (float*)d_out;

  char* ws = (char*)d_ws;
  unsigned*       bars  = (unsigned*)ws;                       // 4096 B (>=769 slots)
  unsigned short* hbuf  = (unsigned short*)(ws + 4096);        // 2*32*512 bf16 = 65536 B
  unsigned short* rbuf  = (unsigned short*)(ws + 4096 + 65536);// 32*256 bf16   = 16384 B
  float*          xibuf = (float*)(ws + 4096 + 65536 + 16384); // 32*480 f32    = 61440 B

  hipMemsetAsync(d_ws, 0, 4096 + 65536 + 16384, stream);       // bars + h0 + r0 = zeros
  hipFuncSetAttribute((const void*)dnc_kernel,
                      hipFuncAttributeMaxDynamicSharedMemorySize, SMEM_BYTES);
  dnc_kernel<<<dim3(NBLK), dim3(BS), SMEM_BYTES, stream>>>(
      src, emb, Wih, Whh, b_lstm, W_xi, b_xi, W_out, b_out, out,
      bars, hbuf, rbuf, xibuf);
}